// Round 31
// baseline (204.251 us; speedup 1.0000x reference)
//
#include <hip/hip_runtime.h>
#include <hip/hip_bf16.h>
#include <cstddef>

#define SP 3136          // 56*56
#define CIN 64
#define COUT 256
#define NB 32
#define NEG_SLOPE 0.01f

typedef __attribute__((ext_vector_type(8))) short short8v;  // 8 bf16 (4 VGPRs)
typedef __attribute__((ext_vector_type(4))) float f32x4;    // MFMA accumulator

__device__ __forceinline__ float bfr(ushort h) {
    union { uint u; float f; } c; c.u = ((uint)h) << 16; return c.f;
}
__device__ __forceinline__ ushort bf_hi(float v) {
    __hip_bfloat16 h = __float2bfloat16(v);
    return *(ushort*)&h;
}

// XOR swizzle: logical 8-ushort group g of row -> physical ushort offset
#define SWZ(row, g) ((((g) ^ ((row) & 7))) * 8)

// direct global->LDS DMA, 16B per lane (dest = wave-uniform base + lane*16)
#define GLOAD_LDS(gp, lp) __builtin_amdgcn_global_load_lds(                    \
    (const __attribute__((address_space(1))) void*)(gp),                       \
    (__attribute__((address_space(3))) void*)(lp), 16, 0, 0)

// ---------------------------------------------------------------------------
// pack_w: W[co][ci][ky][kx] f32 -> fragment-contiguous hi plane (unchanged)
// ---------------------------------------------------------------------------
__global__ __launch_bounds__(256)
void pack_w(const float* __restrict__ W, ushort* __restrict__ wh)
{
    const int id = blockIdx.x * 256 + threadIdx.x;   // 147456 = 9*256*64
    const int ci = id & 63, co = (id >> 6) & 255, tap = id >> 14;
    float v = W[(size_t)(co * 64 + ci) * 9 + tap];
    const int ks = ci >> 5, cig = (ci >> 3) & 3, ce = ci & 7;
    const size_t o = (((size_t)(tap * 2 + ks) * 4 + cig) * 256 + co) * 8 + ce;
    wh[o] = bf_hi(v);
}

// ---------------------------------------------------------------------------
// conv_fused v12: r30's v11 + co-half split for occupancy.
// Hypothesis: v11 was register-capped (acc[4][7] -> ~196 regs/wave -> 2
// waves/SIMD, occupancy 27%). Split co: each block does 128 co (ch half),
// acc[2][7] (~130 regs -> 3 waves/SIMD). B tile staged twice per image-row,
// but input is L2-resident (XCD swizzle, r26: FETCH 27 MB) so duplicate
// staging hits L2 not HBM. Numerics bit-identical. Grid 3584.
// ---------------------------------------------------------------------------
__global__ __launch_bounds__(256, 2)
void conv_fused(const float* __restrict__ xsrc, const float* __restrict__ nsrc,
                const ushort* __restrict__ Wf_hi,
                const float* __restrict__ bias,
                ushort* __restrict__ h1h, ushort* __restrict__ hnh)
{
    __shared__ __align__(16) ushort Bh[4 * 58 * 64]; // 29 KB
    const int tid = threadIdx.x;
    const int w = tid >> 6, l = tid & 63;
    const int bid = blockIdx.x;                      // 0..3583
    const int xcd = bid & 7, s = bid >> 3;           // s 0..447
    const int rp  = s % 28;                          // 0..27
    const int rest = s / 28;                         // 0..15
    const int ch  = rest & 1;                        // co half
    const int img = xcd + 8 * (rest >> 1);           // 0..63
    const int imgb = img & (NB - 1);
    const int y0 = rp * 2, p0 = rp * 112;
    const int co_w = ch * 128 + w * 32;              // wave's co base
    const bool isX = (img < NB);

    const float* __restrict__ src = (isX ? xsrc : nsrc) + (size_t)imgb * CIN * SP;
    ushort* __restrict__ dh = (isX ? h1h : hnh) + (size_t)imgb * COUT * SP;

    // ---- stage B: thread = (j = tid>>6, ci = tid&63), one wrapped row ----
    {
        const int j = tid >> 6, ci = tid & 63;
        const int sy = (y0 + 55 + j) % 56;           // padded row y0+j
        const float* r = src + (size_t)ci * SP + sy * 56;
        const int rowb = (j * 58) << 6;
        ushort first = 0, last = 0;
        #pragma unroll
        for (int q = 0; q < 14; ++q) {
            float4 v = *(const float4*)(r + 4 * q);
            #pragma unroll
            for (int e = 0; e < 4; ++e) {
                const int c = 4 * q + e;
                const float vv = (e == 0) ? v.x : (e == 1) ? v.y : (e == 2) ? v.z : v.w;
                const ushort hv = bf_hi(vv);
                if (c == 0)  first = hv;
                if (c == 55) last  = hv;
                const int x = c + 1;
                Bh[rowb + (x << 6) + ((((ci >> 3) ^ (x & 7))) << 3) + (ci & 7)] = hv;
            }
        }
        // wrap: x=0 <- col 55, x=57 <- col 0 (values already in registers)
        Bh[rowb + (0 << 6)  + ((((ci >> 3) ^ 0)) << 3) + (ci & 7)] = last;
        Bh[rowb + (57 << 6) + ((((ci >> 3) ^ 1)) << 3) + (ci & 7)] = first;
    }
    __syncthreads();                                 // the ONLY barrier

    f32x4 acc[2][7];
    {
        const int rr = (l >> 4) * 4;
        #pragma unroll
        for (int m = 0; m < 2; ++m) {
            const int cb = co_w + 16 * m + rr;
            f32x4 bv = { bias[cb], bias[cb + 1], bias[cb + 2], bias[cb + 3] };
            #pragma unroll
            for (int nf = 0; nf < 7; ++nf) acc[m][nf] = bv;
        }
    }

    // per-nf spatial decomposition (lane-dependent, tap-invariant)
    int b58[7], bx[7];
    #pragma unroll
    for (int nf = 0; nf < 7; ++nf) {
        const int sp = nf * 16 + (l & 15);           // 0..111
        const int ry = (sp >= 56) ? 1 : 0;
        const int xx = sp - ry * 56;
        b58[nf] = ry * 58 + xx;
        bx[nf]  = xx;
    }

    // A-fragment base offsets (iter stride = 4*256*8 = 8192 ushorts)
    size_t aoff[2];
    #pragma unroll
    for (int m = 0; m < 2; ++m)
        aoff[m] = ((size_t)(l >> 4) * 256 + co_w + 16 * m + (l & 15)) * 8;

    short8v cah[2];                                  // current A fragments (hi only)
    #pragma unroll
    for (int m = 0; m < 2; ++m)
        cah[m] = *(const short8v*)(Wf_hi + aoff[m]);

    for (int it = 0; it < 18; ++it) {                // it = tap*2 + ks
        const int tap = it >> 1, ks = it & 1;
        const int dy = tap / 3, dx = tap - dy * 3;
        const int toff = dy * 58 + dx;
        const int grp = ks * 4 + (l >> 4);

        short8v nah[2];                              // prefetch next iter's A
        {
            const size_t po = (size_t)(it < 17 ? it + 1 : it) * 8192;
            #pragma unroll
            for (int m = 0; m < 2; ++m)
                nah[m] = *(const short8v*)(Wf_hi + aoff[m] + po);
        }

        #pragma unroll
        for (int nf = 0; nf < 7; ++nf) {
            const int x  = bx[nf] + dx;
            const int bi = ((b58[nf] + toff) << 6) + ((grp ^ (x & 7)) << 3);
            short8v bh = *(const short8v*)&Bh[bi];
            #pragma unroll
            for (int m = 0; m < 2; ++m)
                acc[m][nf] = __builtin_amdgcn_mfma_f32_16x16x32_bf16(cah[m], bh, acc[m][nf], 0, 0, 0);
        }
        #pragma unroll
        for (int m = 0; m < 2; ++m) cah[m] = nah[m];
    }

    // epilogue: D row=(l>>4)*4+r -> co, col=l&15 -> sp; hi plane only
    const int rr = (l >> 4) * 4, cc = l & 15;
    #pragma unroll
    for (int m = 0; m < 2; ++m) {
        const int cb = co_w + 16 * m + rr;
        #pragma unroll
        for (int nf = 0; nf < 7; ++nf) {
            const int p = p0 + nf * 16 + cc;
            #pragma unroll
            for (int r = 0; r < 4; ++r)
                dh[(size_t)(cb + r) * SP + p] = bf_hi(acc[m][nf][r]);
        }
    }
}

// ---------------------------------------------------------------------------
// gemm_a_mfma v8 (unchanged — DMA+LDS, proven in the 196.8/197.8 totals)
// ---------------------------------------------------------------------------
__global__ __launch_bounds__(256, 2)
void gemm_a_mfma(const ushort* __restrict__ h1h, const ushort* __restrict__ hnh,
                 float* __restrict__ attn)
{
    __shared__ __align__(16) ushort Ah[64][64];
    __shared__ __align__(16) ushort Bh[64][64];
    const int tid = threadIdx.x;
    const int w = tid >> 6, l = tid & 63;
    const int wn = w >> 1, wm = w & 1;              // wave grid 2n x 2m
    const int bid = blockIdx.x;                      // 0..511
    const int xcd = bid & 7, s = bid >> 3;           // s 0..63
    const int tile = s % 16;
    const int img  = xcd + 8 * (s / 16);             // 0..31 (4 groups x 8)
    const int n0 = (tile & 3) * 64, m0 = (tile >> 2) * 64;

    const ushort* __restrict__ mat0 = h1h + ((size_t)img * COUT + n0) * SP;
    const ushort* __restrict__ mat1 = hnh + ((size_t)img * COUT + m0) * SP;

    f32x4 acc[2][2];
    #pragma unroll
    for (int i = 0; i < 2; ++i)
        #pragma unroll
        for (int j = 0; j < 2; ++j) acc[i][j] = (f32x4){0.f, 0.f, 0.f, 0.f};

    // staging: 16 units (mat u>>3, seg u&7); wave w -> units 4w..4w+3.
    const int lr = l >> 3, gp = l & 7;               // lane row-in-seg, phys grp
    const int glog = gp ^ lr;                        // swizzled source group
    const ushort* gptr[4];
    ushort* lptr[4];
    #pragma unroll
    for (int t = 0; t < 4; ++t) {
        const int u = 4 * w + t, mat = u >> 3, seg = u & 7;
        const ushort* ms = (mat == 0) ? mat0 : mat1;
        ushort* lb = (mat == 0) ? &Ah[0][0] : &Bh[0][0];
        gptr[t] = ms + (size_t)(seg * 8 + lr) * SP + glog * 8;
        lptr[t] = lb + seg * 8 * 64;                 // wave-uniform base
    }

    for (int k0 = 0; k0 < SP; k0 += 64) {
        #pragma unroll
        for (int t = 0; t < 4; ++t)
            GLOAD_LDS(gptr[t] + k0, lptr[t]);
        __syncthreads();                             // drains vmcnt before barrier

        #pragma unroll
        for (int ks = 0; ks < 2; ++ks) {
            const int grp = ks * 4 + (l >> 4);
            short8v ahf[2], bhf[2];
            #pragma unroll
            for (int i = 0; i < 2; ++i) {
                const int ar_ = 32 * wn + 16 * i + (l & 15);
                ahf[i] = *(const short8v*)&Ah[ar_][SWZ(ar_, grp)];
                const int br_ = 32 * wm + 16 * i + (l & 15);
                bhf[i] = *(const short8v*)&Bh[br_][SWZ(br_, grp)];
            }
            #pragma unroll
            for (int i = 0; i < 2; ++i)
                #pragma unroll
                for (int j = 0; j < 2; ++j)
                    acc[i][j] = __builtin_amdgcn_mfma_f32_16x16x32_bf16(ahf[i], bhf[j], acc[i][j], 0, 0, 0);
        }
        __syncthreads();
    }

    const int rr = (l >> 4) * 4, cc = l & 15;
    float* __restrict__ aimg = attn + (size_t)img * COUT * COUT;
    #pragma unroll
    for (int i = 0; i < 2; ++i) {
        const int nb = n0 + 32 * wn + 16 * i + rr;
        #pragma unroll
        for (int j = 0; j < 2; ++j) {
            const int m = m0 + 32 * wm + 16 * j + cc;
            #pragma unroll
            for (int r = 0; r < 4; ++r) {
                float v = acc[i][j][r];
                v = (v >= 0.f) ? v : NEG_SLOPE * v;
                aimg[(size_t)(nb + r) * COUT + m] = v;
            }
        }
    }
}

// ---------------------------------------------------------------------------
// softmax_k v2 (unchanged — writes bf16 plane)
// ---------------------------------------------------------------------------
__global__ __launch_bounds__(64)
void softmax_k(const float* __restrict__ attn, ushort* __restrict__ attnb)
{
    const int b = blockIdx.y;
    const int m = blockIdx.x * 64 + threadIdx.x;
    const float* a = attn + (size_t)b * COUT * COUT;
    ushort* ab = attnb + (size_t)b * COUT * COUT;
    float mx = -1e30f;
    for (int n_ = 0; n_ < COUT; ++n_) mx = fmaxf(mx, a[n_ * COUT + m]);
    float s = 0.f;
    for (int n_ = 0; n_ < COUT; ++n_) s += expf(a[n_ * COUT + m] - mx);
    float inv = 1.f / s;
    for (int n_ = 0; n_ < COUT; ++n_)
        ab[n_ * COUT + m] = bf_hi(expf(a[n_ * COUT + m] - mx) * inv);
}

// ---------------------------------------------------------------------------
// gemm_agg_mfma v5 (unchanged from round 26)
// ---------------------------------------------------------------------------
__global__ __launch_bounds__(256, 4)
void gemm_agg_mfma(const ushort* __restrict__ attnb,
                   const ushort* __restrict__ h1h,
                   float* __restrict__ out)
{
    __shared__ __align__(16) ushort Ah[128][64];     // 16 KB, DMA linear+SWZ
    __shared__ __align__(16) ushort Bh[112][76];     // 16.6 KB, stride 76
    const int tid = threadIdx.x, w = tid >> 6, l = tid & 63;
    const int bid = blockIdx.x;                      // 0..1791
    const int xcd = bid & 7, s = bid >> 3;           // s 0..223
    const int local = s % 56;
    const int img  = xcd + 8 * (s / 56);             // 0..31
    const int f0 = (local % 28) * 112;
    const int n0 = (local / 28) * 128;

    const ushort* __restrict__ A  = attnb + (size_t)img * COUT * COUT;
    const ushort* __restrict__ Hh = h1h + (size_t)img * COUT * SP;

    f32x4 acc[2][7];
    #pragma unroll
    for (int nf = 0; nf < 2; ++nf)
        #pragma unroll
        for (int mf = 0; mf < 7; ++mf) acc[nf][mf] = (f32x4){0.f, 0.f, 0.f, 0.f};

    // A DMA staging: 16 units (8 rows each); wave w -> units 4w..4w+3.
    const int lr = l >> 3, gp = l & 7;
    const int glog = gp ^ lr;
    const ushort* agp[4];
    ushort* alp[4];
    #pragma unroll
    for (int t = 0; t < 4; ++t) {
        const int seg = 4 * w + t;
        agp[t] = A + (size_t)(n0 + seg * 8 + lr) * COUT + glog * 8;
        alp[t] = &Ah[0][0] + seg * 8 * 64;           // wave-uniform base
    }
    // B staging (all 256 thr): row k0+bm -> Bh[f][bm], f quarter bfo
    const int bm = tid >> 2, bq = tid & 3, bfo = bq * 28;

    for (int k0 = 0; k0 < COUT; k0 += 64) {
        #pragma unroll
        for (int t = 0; t < 4; ++t)
            GLOAD_LDS(agp[t] + k0, alp[t]);
        {
            const ushort* g = Hh + (size_t)(k0 + bm) * SP + f0 + bfo;
            #pragma unroll
            for (int e = 0; e < 7; ++e) {
                uint2 v = *(const uint2*)(g + 4 * e);
                const ushort* vp = (const ushort*)&v;
                #pragma unroll
                for (int j = 0; j < 4; ++j)
                    Bh[bfo + 4 * e + j][bm] = vp[j];
            }
        }
        __syncthreads();
        #pragma unroll
        for (int ks = 0; ks < 2; ++ks) {
            const int grp = ks * 4 + (l >> 4);
            const int kb = ks * 32 + (l >> 4) * 8;
            short8v ah[2];
            #pragma unroll
            for (int nf = 0; nf < 2; ++nf) {
                const int row = 32 * w + 16 * nf + (l & 15);
                ah[nf] = *(const short8v*)&Ah[row][SWZ(row, grp)];
            }
            #pragma unroll
            for (int mf = 0; mf < 7; ++mf) {
                const int br = mf * 16 + (l & 15);
                short8v bh = *(const short8v*)&Bh[br][kb];
                #pragma unroll
                for (int nf = 0; nf < 2; ++nf)
                    acc[nf][mf] = __builtin_amdgcn_mfma_f32_16x16x32_bf16(ah[nf], bh, acc[nf][mf], 0, 0, 0);
            }
        }
        __syncthreads();
    }

    const int rr = (l >> 4) * 4, cc = l & 15;
    float* __restrict__ orow = out + (size_t)img * COUT * SP;
    #pragma unroll
    for (int nf = 0; nf < 2; ++nf) {
        const int nb = n0 + 32 * w + 16 * nf + rr;
        #pragma unroll
        for (int mf = 0; mf < 7; ++mf) {
            const int f = f0 + 16 * mf + cc;
            #pragma unroll
            for (int r = 0; r < 4; ++r) {
                const int n = nb + r;
                float h = bfr(Hh[(size_t)n * SP + f]);
                orow[(size_t)n * SP + f] = 0.1f * acc[nf][mf][r] + 0.9f * h;
            }
        }
    }
}

// ---------------------------------------------------------------------------
extern "C" void kernel_launch(void* const* d_in, const int* in_sizes, int n_in,
                              void* d_out, int out_size, void* d_ws, size_t ws_size,
                              hipStream_t stream)
{
    const float* x    = (const float*)d_in[0];
    const float* nn   = (const float*)d_in[1];
    const float* W    = (const float*)d_in[2];
    const float* bias = (const float*)d_in[3];
    float* out = (float*)d_out;

    // ws: h1b_hi (51.4 MB) | zone: conv phase Wf_hi (0.59 MB);
    //     gemm phase attn f32 (8.39 MB, overlaps dead Wf) | attnb bf16 (4.2 MB).
    ushort* h1b_hi = (ushort*)d_ws;
    char*   zone   = (char*)(h1b_hi + (size_t)NB * COUT * SP);
    ushort* Wf_hi  = (ushort*)zone;
    float*  attn   = (float*)zone;          // overwrites Wf after convs complete
    ushort* attnb  = (ushort*)(zone + (size_t)NB * COUT * COUT * sizeof(float));
    // d_out (102.8 MB): hnb_hi (51.4) until gemm_agg_mfma overwrites with out f32.
    ushort* hnb_hi = (ushort*)d_out;

    pack_w    <<<576, 256, 0, stream>>>(W, Wf_hi);
    conv_fused<<<3584, 256, 0, stream>>>(x, nn, Wf_hi, bias, h1b_hi, hnb_hi);
    gemm_a_mfma  <<<512, 256, 0, stream>>>(h1b_hi, hnb_hi, attn);
    softmax_k    <<<dim3(4, NB), 64, 0, stream>>>(attn, attnb);
    gemm_agg_mfma<<<1792, 256, 0, stream>>>(attnb, h1b_hi, out);
}

// Round 32
// 197.744 us; speedup vs baseline: 1.0329x; 1.0329x over previous
//
#include <hip/hip_runtime.h>
#include <hip/hip_bf16.h>
#include <cstddef>

#define SP 3136          // 56*56
#define CIN 64
#define COUT 256
#define NB 32
#define NEG_SLOPE 0.01f

typedef __attribute__((ext_vector_type(8))) short short8v;  // 8 bf16 (4 VGPRs)
typedef __attribute__((ext_vector_type(4))) float f32x4;    // MFMA accumulator

__device__ __forceinline__ float bfr(ushort h) {
    union { uint u; float f; } c; c.u = ((uint)h) << 16; return c.f;
}
__device__ __forceinline__ ushort bf_hi(float v) {
    __hip_bfloat16 h = __float2bfloat16(v);
    return *(ushort*)&h;
}

// XOR swizzle: logical 8-ushort group g of row -> physical ushort offset
#define SWZ(row, g) ((((g) ^ ((row) & 7))) * 8)

// direct global->LDS DMA, 16B per lane (dest = wave-uniform base + lane*16)
#define GLOAD_LDS(gp, lp) __builtin_amdgcn_global_load_lds(                    \
    (const __attribute__((address_space(1))) void*)(gp),                       \
    (__attribute__((address_space(3))) void*)(lp), 16, 0, 0)

// ---------------------------------------------------------------------------
// pack_w: W[co][ci][ky][kx] f32 -> fragment-contiguous hi plane
// ---------------------------------------------------------------------------
__global__ __launch_bounds__(256)
void pack_w(const float* __restrict__ W, ushort* __restrict__ wh)
{
    const int id = blockIdx.x * 256 + threadIdx.x;   // 147456 = 9*256*64
    const int ci = id & 63, co = (id >> 6) & 255, tap = id >> 14;
    float v = W[(size_t)(co * 64 + ci) * 9 + tap];
    const int ks = ci >> 5, cig = (ci >> 3) & 3, ce = ci & 7;
    const size_t o = (((size_t)(tap * 2 + ks) * 4 + cig) * 256 + co) * 8 + ce;
    wh[o] = bf_hi(v);
}

// ---------------------------------------------------------------------------
// conv_fused v11 (best-known: 73.5-74 µs; acc[4][7], full 256 co per block,
// XCD swizzle, float4 staging with register wrap, scalar epilogue)
// ---------------------------------------------------------------------------
__global__ __launch_bounds__(256, 2)
void conv_fused(const float* __restrict__ xsrc, const float* __restrict__ nsrc,
                const ushort* __restrict__ Wf_hi,
                const float* __restrict__ bias,
                ushort* __restrict__ h1h, ushort* __restrict__ hnh)
{
    __shared__ __align__(16) ushort Bh[4 * 58 * 64]; // 29 KB
    const int tid = threadIdx.x;
    const int w = tid >> 6, l = tid & 63;
    const int bid = blockIdx.x;                      // 0..1791
    const int xcd = bid & 7, s = bid >> 3;           // s 0..223
    const int rp  = s % 28;                          // 0..27
    const int img = xcd + 8 * (s / 28);              // 0..63
    const int imgb = img & (NB - 1);
    const int y0 = rp * 2, p0 = rp * 112;
    const int co_w = w * 64;                         // wave's co base (4x64=256)
    const bool isX = (img < NB);

    const float* __restrict__ src = (isX ? xsrc : nsrc) + (size_t)imgb * CIN * SP;
    ushort* __restrict__ dh = (isX ? h1h : hnh) + (size_t)imgb * COUT * SP;

    // ---- stage B: thread = (j = tid>>6, ci = tid&63), one wrapped row ----
    {
        const int j = tid >> 6, ci = tid & 63;
        const int sy = (y0 + 55 + j) % 56;           // padded row y0+j
        const float* r = src + (size_t)ci * SP + sy * 56;
        const int rowb = (j * 58) << 6;
        ushort first = 0, last = 0;
        #pragma unroll
        for (int q = 0; q < 14; ++q) {
            float4 v = *(const float4*)(r + 4 * q);
            #pragma unroll
            for (int e = 0; e < 4; ++e) {
                const int c = 4 * q + e;
                const float vv = (e == 0) ? v.x : (e == 1) ? v.y : (e == 2) ? v.z : v.w;
                const ushort hv = bf_hi(vv);
                if (c == 0)  first = hv;
                if (c == 55) last  = hv;
                const int x = c + 1;
                Bh[rowb + (x << 6) + ((((ci >> 3) ^ (x & 7))) << 3) + (ci & 7)] = hv;
            }
        }
        // wrap: x=0 <- col 55, x=57 <- col 0 (values already in registers)
        Bh[rowb + (0 << 6)  + ((((ci >> 3) ^ 0)) << 3) + (ci & 7)] = last;
        Bh[rowb + (57 << 6) + ((((ci >> 3) ^ 1)) << 3) + (ci & 7)] = first;
    }
    __syncthreads();                                 // the ONLY barrier

    f32x4 acc[4][7];
    {
        const int rr = (l >> 4) * 4;
        #pragma unroll
        for (int m = 0; m < 4; ++m) {
            const int cb = co_w + 16 * m + rr;
            f32x4 bv = { bias[cb], bias[cb + 1], bias[cb + 2], bias[cb + 3] };
            #pragma unroll
            for (int nf = 0; nf < 7; ++nf) acc[m][nf] = bv;
        }
    }

    // per-nf spatial decomposition (lane-dependent, tap-invariant)
    int b58[7], bx[7];
    #pragma unroll
    for (int nf = 0; nf < 7; ++nf) {
        const int sp = nf * 16 + (l & 15);           // 0..111
        const int ry = (sp >= 56) ? 1 : 0;
        const int xx = sp - ry * 56;
        b58[nf] = ry * 58 + xx;
        bx[nf]  = xx;
    }

    // A-fragment base offsets (iter stride = 4*256*8 = 8192 ushorts)
    size_t aoff[4];
    #pragma unroll
    for (int m = 0; m < 4; ++m)
        aoff[m] = ((size_t)(l >> 4) * 256 + co_w + 16 * m + (l & 15)) * 8;

    short8v cah[4];                                  // current A fragments (hi only)
    #pragma unroll
    for (int m = 0; m < 4; ++m)
        cah[m] = *(const short8v*)(Wf_hi + aoff[m]);

    for (int it = 0; it < 18; ++it) {                // it = tap*2 + ks
        const int tap = it >> 1, ks = it & 1;
        const int dy = tap / 3, dx = tap - dy * 3;
        const int toff = dy * 58 + dx;
        const int grp = ks * 4 + (l >> 4);

        short8v nah[4];                              // prefetch next iter's A
        {
            const size_t po = (size_t)(it < 17 ? it + 1 : it) * 8192;
            #pragma unroll
            for (int m = 0; m < 4; ++m)
                nah[m] = *(const short8v*)(Wf_hi + aoff[m] + po);
        }

        #pragma unroll
        for (int nf = 0; nf < 7; ++nf) {
            const int x  = bx[nf] + dx;
            const int bi = ((b58[nf] + toff) << 6) + ((grp ^ (x & 7)) << 3);
            short8v bh = *(const short8v*)&Bh[bi];
            #pragma unroll
            for (int m = 0; m < 4; ++m)
                acc[m][nf] = __builtin_amdgcn_mfma_f32_16x16x32_bf16(cah[m], bh, acc[m][nf], 0, 0, 0);
        }
        #pragma unroll
        for (int m = 0; m < 4; ++m) cah[m] = nah[m];
    }

    // epilogue: D row=(l>>4)*4+r -> co, col=l&15 -> sp; hi plane only
    const int rr = (l >> 4) * 4, cc = l & 15;
    #pragma unroll
    for (int m = 0; m < 4; ++m) {
        const int cb = co_w + 16 * m + rr;
        #pragma unroll
        for (int nf = 0; nf < 7; ++nf) {
            const int p = p0 + nf * 16 + cc;
            #pragma unroll
            for (int r = 0; r < 4; ++r)
                dh[(size_t)(cb + r) * SP + p] = bf_hi(acc[m][nf][r]);
        }
    }
}

// ---------------------------------------------------------------------------
// gemm_a_mfma v8 (best-known: DMA+LDS staging, XCD swizzle)
// ---------------------------------------------------------------------------
__global__ __launch_bounds__(256, 2)
void gemm_a_mfma(const ushort* __restrict__ h1h, const ushort* __restrict__ hnh,
                 float* __restrict__ attn)
{
    __shared__ __align__(16) ushort Ah[64][64];
    __shared__ __align__(16) ushort Bh[64][64];
    const int tid = threadIdx.x;
    const int w = tid >> 6, l = tid & 63;
    const int wn = w >> 1, wm = w & 1;              // wave grid 2n x 2m
    const int bid = blockIdx.x;                      // 0..511
    const int xcd = bid & 7, s = bid >> 3;           // s 0..63
    const int tile = s % 16;
    const int img  = xcd + 8 * (s / 16);             // 0..31 (4 groups x 8)
    const int n0 = (tile & 3) * 64, m0 = (tile >> 2) * 64;

    const ushort* __restrict__ mat0 = h1h + ((size_t)img * COUT + n0) * SP;
    const ushort* __restrict__ mat1 = hnh + ((size_t)img * COUT + m0) * SP;

    f32x4 acc[2][2];
    #pragma unroll
    for (int i = 0; i < 2; ++i)
        #pragma unroll
        for (int j = 0; j < 2; ++j) acc[i][j] = (f32x4){0.f, 0.f, 0.f, 0.f};

    // staging: 16 units (mat u>>3, seg u&7); wave w -> units 4w..4w+3.
    const int lr = l >> 3, gp = l & 7;               // lane row-in-seg, phys grp
    const int glog = gp ^ lr;                        // swizzled source group
    const ushort* gptr[4];
    ushort* lptr[4];
    #pragma unroll
    for (int t = 0; t < 4; ++t) {
        const int u = 4 * w + t, mat = u >> 3, seg = u & 7;
        const ushort* ms = (mat == 0) ? mat0 : mat1;
        ushort* lb = (mat == 0) ? &Ah[0][0] : &Bh[0][0];
        gptr[t] = ms + (size_t)(seg * 8 + lr) * SP + glog * 8;
        lptr[t] = lb + seg * 8 * 64;                 // wave-uniform base
    }

    for (int k0 = 0; k0 < SP; k0 += 64) {
        #pragma unroll
        for (int t = 0; t < 4; ++t)
            GLOAD_LDS(gptr[t] + k0, lptr[t]);
        __syncthreads();                             // drains vmcnt before barrier

        #pragma unroll
        for (int ks = 0; ks < 2; ++ks) {
            const int grp = ks * 4 + (l >> 4);
            short8v ahf[2], bhf[2];
            #pragma unroll
            for (int i = 0; i < 2; ++i) {
                const int ar_ = 32 * wn + 16 * i + (l & 15);
                ahf[i] = *(const short8v*)&Ah[ar_][SWZ(ar_, grp)];
                const int br_ = 32 * wm + 16 * i + (l & 15);
                bhf[i] = *(const short8v*)&Bh[br_][SWZ(br_, grp)];
            }
            #pragma unroll
            for (int i = 0; i < 2; ++i)
                #pragma unroll
                for (int j = 0; j < 2; ++j)
                    acc[i][j] = __builtin_amdgcn_mfma_f32_16x16x32_bf16(ahf[i], bhf[j], acc[i][j], 0, 0, 0);
        }
        __syncthreads();
    }

    const int rr = (l >> 4) * 4, cc = l & 15;
    float* __restrict__ aimg = attn + (size_t)img * COUT * COUT;
    #pragma unroll
    for (int i = 0; i < 2; ++i) {
        const int nb = n0 + 32 * wn + 16 * i + rr;
        #pragma unroll
        for (int j = 0; j < 2; ++j) {
            const int m = m0 + 32 * wm + 16 * j + cc;
            #pragma unroll
            for (int r = 0; r < 4; ++r) {
                float v = acc[i][j][r];
                v = (v >= 0.f) ? v : NEG_SLOPE * v;
                aimg[(size_t)(nb + r) * COUT + m] = v;
            }
        }
    }
}

// ---------------------------------------------------------------------------
// softmax_k v2 (writes bf16 plane)
// ---------------------------------------------------------------------------
__global__ __launch_bounds__(64)
void softmax_k(const float* __restrict__ attn, ushort* __restrict__ attnb)
{
    const int b = blockIdx.y;
    const int m = blockIdx.x * 64 + threadIdx.x;
    const float* a = attn + (size_t)b * COUT * COUT;
    ushort* ab = attnb + (size_t)b * COUT * COUT;
    float mx = -1e30f;
    for (int n_ = 0; n_ < COUT; ++n_) mx = fmaxf(mx, a[n_ * COUT + m]);
    float s = 0.f;
    for (int n_ = 0; n_ < COUT; ++n_) s += expf(a[n_ * COUT + m] - mx);
    float inv = 1.f / s;
    for (int n_ = 0; n_ < COUT; ++n_)
        ab[n_ * COUT + m] = bf_hi(expf(a[n_ * COUT + m] - mx) * inv);
}

// ---------------------------------------------------------------------------
// gemm_agg_mfma v5 (best-known: DMA-A, stride-76 B, XCD-img grid)
// ---------------------------------------------------------------------------
__global__ __launch_bounds__(256, 4)
void gemm_agg_mfma(const ushort* __restrict__ attnb,
                   const ushort* __restrict__ h1h,
                   float* __restrict__ out)
{
    __shared__ __align__(16) ushort Ah[128][64];     // 16 KB, DMA linear+SWZ
    __shared__ __align__(16) ushort Bh[112][76];     // 16.6 KB, stride 76
    const int tid = threadIdx.x, w = tid >> 6, l = tid & 63;
    const int bid = blockIdx.x;                      // 0..1791
    const int xcd = bid & 7, s = bid >> 3;           // s 0..223
    const int local = s % 56;
    const int img  = xcd + 8 * (s / 56);             // 0..31
    const int f0 = (local % 28) * 112;
    const int n0 = (local / 28) * 128;

    const ushort* __restrict__ A  = attnb + (size_t)img * COUT * COUT;
    const ushort* __restrict__ Hh = h1h + (size_t)img * COUT * SP;

    f32x4 acc[2][7];
    #pragma unroll
    for (int nf = 0; nf < 2; ++nf)
        #pragma unroll
        for (int mf = 0; mf < 7; ++mf) acc[nf][mf] = (f32x4){0.f, 0.f, 0.f, 0.f};

    // A DMA staging: 16 units (8 rows each); wave w -> units 4w..4w+3.
    const int lr = l >> 3, gp = l & 7;
    const int glog = gp ^ lr;
    const ushort* agp[4];
    ushort* alp[4];
    #pragma unroll
    for (int t = 0; t < 4; ++t) {
        const int seg = 4 * w + t;
        agp[t] = A + (size_t)(n0 + seg * 8 + lr) * COUT + glog * 8;
        alp[t] = &Ah[0][0] + seg * 8 * 64;           // wave-uniform base
    }
    // B staging (all 256 thr): row k0+bm -> Bh[f][bm], f quarter bfo
    const int bm = tid >> 2, bq = tid & 3, bfo = bq * 28;

    for (int k0 = 0; k0 < COUT; k0 += 64) {
        #pragma unroll
        for (int t = 0; t < 4; ++t)
            GLOAD_LDS(agp[t] + k0, alp[t]);
        {
            const ushort* g = Hh + (size_t)(k0 + bm) * SP + f0 + bfo;
            #pragma unroll
            for (int e = 0; e < 7; ++e) {
                uint2 v = *(const uint2*)(g + 4 * e);
                const ushort* vp = (const ushort*)&v;
                #pragma unroll
                for (int j = 0; j < 4; ++j)
                    Bh[bfo + 4 * e + j][bm] = vp[j];
            }
        }
        __syncthreads();
        #pragma unroll
        for (int ks = 0; ks < 2; ++ks) {
            const int grp = ks * 4 + (l >> 4);
            const int kb = ks * 32 + (l >> 4) * 8;
            short8v ah[2];
            #pragma unroll
            for (int nf = 0; nf < 2; ++nf) {
                const int row = 32 * w + 16 * nf + (l & 15);
                ah[nf] = *(const short8v*)&Ah[row][SWZ(row, grp)];
            }
            #pragma unroll
            for (int mf = 0; mf < 7; ++mf) {
                const int br = mf * 16 + (l & 15);
                short8v bh = *(const short8v*)&Bh[br][kb];
                #pragma unroll
                for (int nf = 0; nf < 2; ++nf)
                    acc[nf][mf] = __builtin_amdgcn_mfma_f32_16x16x32_bf16(ah[nf], bh, acc[nf][mf], 0, 0, 0);
            }
        }
        __syncthreads();
    }

    const int rr = (l >> 4) * 4, cc = l & 15;
    float* __restrict__ orow = out + (size_t)img * COUT * SP;
    #pragma unroll
    for (int nf = 0; nf < 2; ++nf) {
        const int nb = n0 + 32 * w + 16 * nf + rr;
        #pragma unroll
        for (int mf = 0; mf < 7; ++mf) {
            const int f = f0 + 16 * mf + cc;
            #pragma unroll
            for (int r = 0; r < 4; ++r) {
                const int n = nb + r;
                float h = bfr(Hh[(size_t)n * SP + f]);
                orow[(size_t)n * SP + f] = 0.1f * acc[nf][mf][r] + 0.9f * h;
            }
        }
    }
}

// ---------------------------------------------------------------------------
extern "C" void kernel_launch(void* const* d_in, const int* in_sizes, int n_in,
                              void* d_out, int out_size, void* d_ws, size_t ws_size,
                              hipStream_t stream)
{
    const float* x    = (const float*)d_in[0];
    const float* nn   = (const float*)d_in[1];
    const float* W    = (const float*)d_in[2];
    const float* bias = (const float*)d_in[3];
    float* out = (float*)d_out;

    // ws: h1b_hi (51.4 MB) | zone: conv phase Wf_hi (0.59 MB);
    //     gemm phase attn f32 (8.39 MB, overlaps dead Wf) | attnb bf16 (4.2 MB).
    ushort* h1b_hi = (ushort*)d_ws;
    char*   zone   = (char*)(h1b_hi + (size_t)NB * COUT * SP);
    ushort* Wf_hi  = (ushort*)zone;
    float*  attn   = (float*)zone;          // overwrites Wf after convs complete
    ushort* attnb  = (ushort*)(zone + (size_t)NB * COUT * COUT * sizeof(float));
    // d_out (102.8 MB): hnb_hi (51.4) until gemm_agg_mfma overwrites with out f32.
    ushort* hnb_hi = (ushort*)d_out;

    pack_w    <<<576, 256, 0, stream>>>(W, Wf_hi);
    conv_fused<<<1792, 256, 0, stream>>>(x, nn, Wf_hi, bias, h1b_hi, hnb_hi);
    gemm_a_mfma  <<<512, 256, 0, stream>>>(h1b_hi, hnb_hi, attn);
    softmax_k    <<<dim3(4, NB), 64, 0, stream>>>(attn, attnb);
    gemm_agg_mfma<<<1792, 256, 0, stream>>>(attnb, h1b_hi, out);
}